// Round 2
// baseline (5751.120 us; speedup 1.0000x reference)
//
#include <hip/hip_runtime.h>
#include <math.h>

#define BB 4
#define NN 8192
#define DD 256
#define KK 512
#define NITERS 10

#define MT 64     // points per block in assign
#define KT 128    // clusters per k-chunk
#define DC 32     // d chunk staged in LDS

#define XSTR 68   // padded LDS stride for xs[d][m]
#define CSTR 132  // padded LDS stride for cs[d][k]
#define TAU 0.0625f   // top2 margin below which we re-rank in f64

// ---------------- init: centers0 = x[:, :K, :] ----------------
__global__ __launch_bounds__(256) void init_centers_k(const float* __restrict__ x,
                                                      float* __restrict__ centers) {
    int bk = blockIdx.x;          // 0 .. B*K-1
    int b  = bk >> 9;             // /512
    int k  = bk & 511;
    centers[(size_t)bk * DD + threadIdx.x] = x[((size_t)b * NN + k) * DD + threadIdx.x];
}

// ---------------- row sum of squares, numpy-pairwise order ----------------
__global__ __launch_bounds__(256) void rowsumsq_k(const float* __restrict__ rows,
                                                  float* __restrict__ out, int nrows) {
    int r = blockIdx.x * 256 + threadIdx.x;
    if (r >= nrows) return;
    const float* p = rows + (size_t)r * DD;
    float total = 0.f;
    #pragma unroll
    for (int h = 0; h < 2; ++h) {
        float a[8];
        #pragma unroll
        for (int j = 0; j < 8; ++j) a[j] = 0.f;
        for (int i = 0; i < 128; i += 8) {
            #pragma unroll
            for (int j = 0; j < 8; ++j) {
                float v  = p[h * 128 + i + j];
                float sq = __fmul_rn(v, v);
                a[j] = __fadd_rn(a[j], sq);
            }
        }
        float s = __fadd_rn(__fadd_rn(__fadd_rn(a[0], a[1]), __fadd_rn(a[2], a[3])),
                            __fadd_rn(__fadd_rn(a[4], a[5]), __fadd_rn(a[6], a[7])));
        total = __fadd_rn(total, s);
    }
    out[r] = total;
}

// ---------------- fused distance / top-2 argmin, flag marginal points ------
__global__ __launch_bounds__(256) void assign_k(
    const float* __restrict__ x, const float* __restrict__ centers,
    const float* __restrict__ x2g, const float* __restrict__ c2g,
    int* __restrict__ labels, int* __restrict__ flagcnt, int* __restrict__ flaglist)
{
    __shared__ float xs[DC][XSTR];
    __shared__ float cs[DC][CSTR];

    const int tid = threadIdx.x;
    const int tk  = tid & 15;
    const int tm  = tid >> 4;
    const int bx  = blockIdx.x;
    const int b   = bx >> 7;
    const int m0  = (bx & 127) * MT;

    const float* xb = x       + (size_t)b * NN * DD;
    const float* cb = centers + (size_t)b * KK * DD;

    float x2m[4];
    #pragma unroll
    for (int i = 0; i < 4; ++i) x2m[i] = x2g[b * NN + m0 + tm * 4 + i];

    float rv1[4], rv2[4];
    int   rk1[4];
    #pragma unroll
    for (int i = 0; i < 4; ++i) { rv1[i] = __builtin_inff(); rv2[i] = __builtin_inff(); rk1[i] = 0x7fffffff; }

    const int lrow = tid >> 3;
    const int lcol = (tid & 7) * 4;

    for (int kc = 0; kc < KK; kc += KT) {
        float acc[4][8];
        #pragma unroll
        for (int i = 0; i < 4; ++i)
            #pragma unroll
            for (int j = 0; j < 8; ++j) acc[i][j] = 0.f;

        for (int d0 = 0; d0 < DD; d0 += DC) {
            __syncthreads();
            #pragma unroll
            for (int p = 0; p < 2; ++p) {
                int r = lrow + p * 32;
                float4 v = *(const float4*)(xb + (size_t)(m0 + r) * DD + d0 + lcol);
                xs[lcol + 0][r] = v.x; xs[lcol + 1][r] = v.y;
                xs[lcol + 2][r] = v.z; xs[lcol + 3][r] = v.w;
            }
            #pragma unroll
            for (int p = 0; p < 4; ++p) {
                int r = lrow + p * 32;
                float4 v = *(const float4*)(cb + (size_t)(kc + r) * DD + d0 + lcol);
                cs[lcol + 0][r] = v.x; cs[lcol + 1][r] = v.y;
                cs[lcol + 2][r] = v.z; cs[lcol + 3][r] = v.w;
            }
            __syncthreads();
            #pragma unroll
            for (int d = 0; d < DC; ++d) {
                const float4 xv  = *(const float4*)&xs[d][tm * 4];
                const float4 ca  = *(const float4*)&cs[d][tk * 4];
                const float4 cbv = *(const float4*)&cs[d][64 + tk * 4];
                float xf[4] = {xv.x, xv.y, xv.z, xv.w};
                float cf[8] = {ca.x, ca.y, ca.z, ca.w, cbv.x, cbv.y, cbv.z, cbv.w};
                #pragma unroll
                for (int i = 0; i < 4; ++i)
                    #pragma unroll
                    for (int j = 0; j < 8; ++j)
                        acc[i][j] += xf[i] * cf[j];
            }
        }

        float c2v[8];
        #pragma unroll
        for (int j = 0; j < 4; ++j) c2v[j]     = c2g[b * KK + kc + tk * 4 + j];
        #pragma unroll
        for (int j = 0; j < 4; ++j) c2v[4 + j] = c2g[b * KK + kc + 64 + tk * 4 + j];

        #pragma unroll
        for (int i = 0; i < 4; ++i) {
            float v1 = __builtin_inff(), v2 = __builtin_inff();
            int   k1 = 0x7fffffff;
            #pragma unroll
            for (int j = 0; j < 8; ++j) {
                int kidx = kc + ((j < 4) ? (tk * 4 + j) : (64 + tk * 4 + (j - 4)));
                float t    = __fmul_rn(2.0f, acc[i][j]);
                float cand = __fadd_rn(__fsub_rn(x2m[i], t), c2v[j]);
                if (cand < v1 || (cand == v1 && kidx < k1)) { v2 = v1; v1 = cand; k1 = kidx; }
                else if (cand < v2) v2 = cand;
            }
            #pragma unroll
            for (int off = 1; off < 16; off <<= 1) {
                float ov1 = __shfl_xor(v1, off, 64);
                int   ok1 = __shfl_xor(k1, off, 64);
                float ov2 = __shfl_xor(v2, off, 64);
                if (ov1 < v1 || (ov1 == v1 && ok1 < k1)) { v2 = fminf(v1, ov2); v1 = ov1; k1 = ok1; }
                else { v2 = fminf(v2, ov1); }
            }
            // merge into running top-2
            if (v1 < rv1[i] || (v1 == rv1[i] && k1 < rk1[i])) {
                rv2[i] = fminf(rv1[i], v2); rv1[i] = v1; rk1[i] = k1;
            } else {
                rv2[i] = fminf(rv2[i], v1);
            }
        }
    }

    if (tk == 0) {
        #pragma unroll
        for (int i = 0; i < 4; ++i) {
            int g = b * NN + m0 + tm * 4 + i;
            labels[g] = rk1[i];
            if (rv2[i] - rv1[i] < TAU) {
                int pos = atomicAdd(flagcnt, 1);
                flaglist[pos] = g;
            }
        }
    }
}

// ---------------- exact (f64) re-rank of flagged points --------------------
__global__ __launch_bounds__(256) void refine_k(const float* __restrict__ x,
                                                const float* __restrict__ centers,
                                                const int* __restrict__ flagcnt,
                                                const int* __restrict__ flaglist,
                                                int* __restrict__ labels) {
    __shared__ float  xsr[DD];
    __shared__ double sv[256];
    __shared__ int    si[256];
    const int t = threadIdx.x;
    const int cnt = flagcnt[0];
    for (int idx = blockIdx.x; idx < cnt; idx += gridDim.x) {
        const int g = flaglist[idx];
        const int b = g >> 13;            // /NN
        __syncthreads();
        xsr[t] = x[(size_t)g * DD + t];
        __syncthreads();
        const float* cbase = centers + (size_t)b * KK * DD;
        double bestv = 1e300; int bestk = 0x7fffffff;
        #pragma unroll
        for (int h = 0; h < 2; ++h) {
            int k = t + h * 256;
            const float* cr = cbase + (size_t)k * DD;
            double a0 = 0, a1 = 0, a2 = 0, a3 = 0;
            for (int d = 0; d < DD; d += 4) {
                double f0 = (double)xsr[d + 0] - (double)cr[d + 0];
                double f1 = (double)xsr[d + 1] - (double)cr[d + 1];
                double f2 = (double)xsr[d + 2] - (double)cr[d + 2];
                double f3 = (double)xsr[d + 3] - (double)cr[d + 3];
                a0 += f0 * f0; a1 += f1 * f1; a2 += f2 * f2; a3 += f3 * f3;
            }
            double dist = (a0 + a1) + (a2 + a3);
            if (dist < bestv || (dist == bestv && k < bestk)) { bestv = dist; bestk = k; }
        }
        sv[t] = bestv; si[t] = bestk;
        __syncthreads();
        for (int s = 128; s > 0; s >>= 1) {
            if (t < s) {
                if (sv[t + s] < sv[t] || (sv[t + s] == sv[t] && si[t + s] < si[t])) {
                    sv[t] = sv[t + s]; si[t] = si[t + s];
                }
            }
            __syncthreads();
        }
        if (t == 0) labels[g] = si[0];
    }
}

// ------- stable counting-sort member lists (n-ascending) — 1 wave/batch -----
__global__ __launch_bounds__(64) void build_lists_k(const int* __restrict__ labels,
                                                    int* __restrict__ counts,
                                                    int* __restrict__ offsets,
                                                    int* __restrict__ idxlist) {
    __shared__ int hist[KK];
    __shared__ int offs[KK];
    __shared__ int curs[KK];
    const int b = blockIdx.x, t = threadIdx.x;
    for (int k = t; k < KK; k += 64) { hist[k] = 0; curs[k] = 0; }
    __syncthreads();
    const int* lb = labels + b * NN;
    for (int n = t; n < NN; n += 64) atomicAdd(&hist[lb[n]], 1);
    __syncthreads();
    if (t == 0) {
        int run = 0;
        for (int k = 0; k < KK; ++k) { offs[k] = run; run += hist[k]; }
    }
    __syncthreads();
    for (int k = t; k < KK; k += 64) {
        counts[b * KK + k]  = hist[k];
        offsets[b * KK + k] = offs[k];
    }
    // stable scatter, single wave, n ascending
    for (int c = 0; c < NN / 64; ++c) {
        int n = c * 64 + t;
        int l = lb[n];
        int rank = 0, tot = 0;
        for (int j = 0; j < 64; ++j) {
            int lj = __shfl(l, j, 64);
            rank += (lj == l && j < t) ? 1 : 0;
            tot  += (lj == l) ? 1 : 0;
        }
        int base = curs[l];                       // read before leader update
        idxlist[b * NN + offs[l] + base + rank] = n;
        if (rank == 0) curs[l] = base + tot;      // leader of this label
    }
}

// ------- centers update: ordered (n-ascending) sums → bit-exact vs np ------
__global__ __launch_bounds__(256) void centers_update_k(const float* __restrict__ x,
                                                        float* __restrict__ centers,
                                                        const int* __restrict__ counts,
                                                        const int* __restrict__ offsets,
                                                        const int* __restrict__ idxlist,
                                                        int* __restrict__ flagcnt) {
    const int bk = blockIdx.x;
    const int b  = bk >> 9;
    const int d  = threadIdx.x;
    if (bk == 0 && d == 0) flagcnt[0] = 0;   // reset for next assign pass
    const int cnt = counts[bk];
    if (cnt > 0) {
        const int* il = idxlist + b * NN + offsets[bk];
        float s = 0.f;
        for (int j = 0; j < cnt; ++j) {
            int n = il[j];
            s = __fadd_rn(s, x[((size_t)b * NN + n) * DD + d]);
        }
        centers[(size_t)bk * DD + d] = s / (float)cnt;
    }
}

__global__ __launch_bounds__(256) void labels_to_float_k(const int* __restrict__ labels,
                                                         float* __restrict__ out) {
    int i = blockIdx.x * 256 + threadIdx.x;
    out[i] = (float)labels[i];
}

__global__ __launch_bounds__(256) void copy_centers_k(const float* __restrict__ centers,
                                                      float* __restrict__ out) {
    size_t i = (size_t)blockIdx.x * 256 + threadIdx.x;
    out[i] = centers[i];
}

extern "C" void kernel_launch(void* const* d_in, const int* in_sizes, int n_in,
                              void* d_out, int out_size, void* d_ws, size_t ws_size,
                              hipStream_t stream) {
    const float* x = (const float*)d_in[0];
    float* out = (float*)d_out;
    float* ws  = (float*)d_ws;

    // ws layout
    float* centers = ws;                                   // BB*KK*DD
    float* c2      = centers + (size_t)BB * KK * DD;       // BB*KK
    float* x2      = c2 + BB * KK;                         // BB*NN
    int*   labels  = (int*)(x2 + BB * NN);                 // BB*NN
    int*   flagcnt = labels + BB * NN;                     // 64
    int*   flaglist= flagcnt + 64;                         // BB*NN
    int*   counts  = flaglist + BB * NN;                   // BB*KK
    int*   offsets = counts + BB * KK;                     // BB*KK
    int*   idxlist = offsets + BB * KK;                    // BB*NN

    hipMemsetAsync(flagcnt, 0, 64 * sizeof(int), stream);

    init_centers_k<<<BB * KK, 256, 0, stream>>>(x, centers);
    rowsumsq_k<<<(BB * NN + 255) / 256, 256, 0, stream>>>(x, x2, BB * NN);

    for (int it = 0; it < NITERS; ++it) {
        rowsumsq_k<<<(BB * KK + 255) / 256, 256, 0, stream>>>(centers, c2, BB * KK);
        assign_k<<<BB * (NN / MT), 256, 0, stream>>>(x, centers, x2, c2,
                                                     labels, flagcnt, flaglist);
        refine_k<<<64, 256, 0, stream>>>(x, centers, flagcnt, flaglist, labels);
        build_lists_k<<<BB, 64, 0, stream>>>(labels, counts, offsets, idxlist);
        centers_update_k<<<BB * KK, 256, 0, stream>>>(x, centers, counts, offsets,
                                                      idxlist, flagcnt);
    }

    rowsumsq_k<<<(BB * KK + 255) / 256, 256, 0, stream>>>(centers, c2, BB * KK);
    assign_k<<<BB * (NN / MT), 256, 0, stream>>>(x, centers, x2, c2,
                                                 labels, flagcnt, flaglist);
    refine_k<<<64, 256, 0, stream>>>(x, centers, flagcnt, flaglist, labels);

    labels_to_float_k<<<BB * NN / 256, 256, 0, stream>>>(labels, out);
    copy_centers_k<<<BB * KK * DD / 256, 256, 0, stream>>>(centers, out + BB * NN);
}

// Round 3
// 2902.585 us; speedup vs baseline: 1.9814x; 1.9814x over previous
//
#include <hip/hip_runtime.h>
#include <math.h>

#define BB 4
#define NN 8192
#define DD 256
#define KK 512
#define NITERS 10

#define MT 64     // points per block in assign
#define KT 128    // clusters per k-chunk
#define DC 32     // d chunk staged in LDS

#define XSTR 68   // padded LDS stride for xs[d][m]
#define CSTR 132  // padded LDS stride for cs[d][k]
#define TAU 0.0625f   // top2 margin below which we re-rank in f64

#define NCH 128   // 64-point chunks per batch (NN/64)

// ---------------- init: centers0 = x[:, :K, :] ----------------
__global__ __launch_bounds__(256) void init_centers_k(const float* __restrict__ x,
                                                      float* __restrict__ centers) {
    int bk = blockIdx.x;
    int b  = bk >> 9;
    int k  = bk & 511;
    centers[(size_t)bk * DD + threadIdx.x] = x[((size_t)b * NN + k) * DD + threadIdx.x];
}

// ---------------- row sum of squares, numpy-pairwise order ----------------
__global__ __launch_bounds__(256) void rowsumsq_k(const float* __restrict__ rows,
                                                  float* __restrict__ out, int nrows) {
    int r = blockIdx.x * 256 + threadIdx.x;
    if (r >= nrows) return;
    const float* p = rows + (size_t)r * DD;
    float total = 0.f;
    #pragma unroll
    for (int h = 0; h < 2; ++h) {
        float a[8];
        #pragma unroll
        for (int j = 0; j < 8; ++j) a[j] = 0.f;
        for (int i = 0; i < 128; i += 8) {
            #pragma unroll
            for (int j = 0; j < 8; ++j) {
                float v  = p[h * 128 + i + j];
                float sq = __fmul_rn(v, v);
                a[j] = __fadd_rn(a[j], sq);
            }
        }
        float s = __fadd_rn(__fadd_rn(__fadd_rn(a[0], a[1]), __fadd_rn(a[2], a[3])),
                            __fadd_rn(__fadd_rn(a[4], a[5]), __fadd_rn(a[6], a[7])));
        total = __fadd_rn(total, s);
    }
    out[r] = total;
}

// ---------------- fused distance / top-2 argmin, flag marginal points ------
__global__ __launch_bounds__(256) void assign_k(
    const float* __restrict__ x, const float* __restrict__ centers,
    const float* __restrict__ x2g, const float* __restrict__ c2g,
    int* __restrict__ labels, int* __restrict__ flagcnt, int* __restrict__ flaglist)
{
    __shared__ float xs[DC][XSTR];
    __shared__ float cs[DC][CSTR];

    const int tid = threadIdx.x;
    const int tk  = tid & 15;
    const int tm  = tid >> 4;
    const int bx  = blockIdx.x;
    const int b   = bx >> 7;
    const int m0  = (bx & 127) * MT;

    const float* xb = x       + (size_t)b * NN * DD;
    const float* cb = centers + (size_t)b * KK * DD;

    float x2m[4];
    #pragma unroll
    for (int i = 0; i < 4; ++i) x2m[i] = x2g[b * NN + m0 + tm * 4 + i];

    float rv1[4], rv2[4];
    int   rk1[4];
    #pragma unroll
    for (int i = 0; i < 4; ++i) { rv1[i] = __builtin_inff(); rv2[i] = __builtin_inff(); rk1[i] = 0x7fffffff; }

    const int lrow = tid >> 3;
    const int lcol = (tid & 7) * 4;

    for (int kc = 0; kc < KK; kc += KT) {
        float acc[4][8];
        #pragma unroll
        for (int i = 0; i < 4; ++i)
            #pragma unroll
            for (int j = 0; j < 8; ++j) acc[i][j] = 0.f;

        for (int d0 = 0; d0 < DD; d0 += DC) {
            __syncthreads();
            #pragma unroll
            for (int p = 0; p < 2; ++p) {
                int r = lrow + p * 32;
                float4 v = *(const float4*)(xb + (size_t)(m0 + r) * DD + d0 + lcol);
                xs[lcol + 0][r] = v.x; xs[lcol + 1][r] = v.y;
                xs[lcol + 2][r] = v.z; xs[lcol + 3][r] = v.w;
            }
            #pragma unroll
            for (int p = 0; p < 4; ++p) {
                int r = lrow + p * 32;
                float4 v = *(const float4*)(cb + (size_t)(kc + r) * DD + d0 + lcol);
                cs[lcol + 0][r] = v.x; cs[lcol + 1][r] = v.y;
                cs[lcol + 2][r] = v.z; cs[lcol + 3][r] = v.w;
            }
            __syncthreads();
            #pragma unroll
            for (int d = 0; d < DC; ++d) {
                const float4 xv  = *(const float4*)&xs[d][tm * 4];
                const float4 ca  = *(const float4*)&cs[d][tk * 4];
                const float4 cbv = *(const float4*)&cs[d][64 + tk * 4];
                float xf[4] = {xv.x, xv.y, xv.z, xv.w};
                float cf[8] = {ca.x, ca.y, ca.z, ca.w, cbv.x, cbv.y, cbv.z, cbv.w};
                #pragma unroll
                for (int i = 0; i < 4; ++i)
                    #pragma unroll
                    for (int j = 0; j < 8; ++j)
                        acc[i][j] += xf[i] * cf[j];
            }
        }

        float c2v[8];
        #pragma unroll
        for (int j = 0; j < 4; ++j) c2v[j]     = c2g[b * KK + kc + tk * 4 + j];
        #pragma unroll
        for (int j = 0; j < 4; ++j) c2v[4 + j] = c2g[b * KK + kc + 64 + tk * 4 + j];

        #pragma unroll
        for (int i = 0; i < 4; ++i) {
            float v1 = __builtin_inff(), v2 = __builtin_inff();
            int   k1 = 0x7fffffff;
            #pragma unroll
            for (int j = 0; j < 8; ++j) {
                int kidx = kc + ((j < 4) ? (tk * 4 + j) : (64 + tk * 4 + (j - 4)));
                float t    = __fmul_rn(2.0f, acc[i][j]);
                float cand = __fadd_rn(__fsub_rn(x2m[i], t), c2v[j]);
                if (cand < v1 || (cand == v1 && kidx < k1)) { v2 = v1; v1 = cand; k1 = kidx; }
                else if (cand < v2) v2 = cand;
            }
            #pragma unroll
            for (int off = 1; off < 16; off <<= 1) {
                float ov1 = __shfl_xor(v1, off, 64);
                int   ok1 = __shfl_xor(k1, off, 64);
                float ov2 = __shfl_xor(v2, off, 64);
                if (ov1 < v1 || (ov1 == v1 && ok1 < k1)) { v2 = fminf(v1, ov2); v1 = ov1; k1 = ok1; }
                else { v2 = fminf(v2, ov1); }
            }
            if (v1 < rv1[i] || (v1 == rv1[i] && k1 < rk1[i])) {
                rv2[i] = fminf(rv1[i], v2); rv1[i] = v1; rk1[i] = k1;
            } else {
                rv2[i] = fminf(rv2[i], v1);
            }
        }
    }

    if (tk == 0) {
        #pragma unroll
        for (int i = 0; i < 4; ++i) {
            int g = b * NN + m0 + tm * 4 + i;
            labels[g] = rk1[i];
            if (rv2[i] - rv1[i] < TAU) {
                int pos = atomicAdd(flagcnt, 1);
                flaglist[pos] = g;
            }
        }
    }
}

// ---------------- exact (f64) re-rank of flagged points --------------------
__global__ __launch_bounds__(256) void refine_k(const float* __restrict__ x,
                                                const float* __restrict__ centers,
                                                const int* __restrict__ flagcnt,
                                                const int* __restrict__ flaglist,
                                                int* __restrict__ labels) {
    __shared__ float  xsr[DD];
    __shared__ double sv[256];
    __shared__ int    si[256];
    const int t = threadIdx.x;
    const int cnt = flagcnt[0];
    for (int idx = blockIdx.x; idx < cnt; idx += gridDim.x) {
        const int g = flaglist[idx];
        const int b = g >> 13;
        __syncthreads();
        xsr[t] = x[(size_t)g * DD + t];
        __syncthreads();
        const float* cbase = centers + (size_t)b * KK * DD;
        double bestv = 1e300; int bestk = 0x7fffffff;
        #pragma unroll
        for (int h = 0; h < 2; ++h) {
            int k = t + h * 256;
            const float* cr = cbase + (size_t)k * DD;
            double a0 = 0, a1 = 0, a2 = 0, a3 = 0;
            for (int d = 0; d < DD; d += 4) {
                double f0 = (double)xsr[d + 0] - (double)cr[d + 0];
                double f1 = (double)xsr[d + 1] - (double)cr[d + 1];
                double f2 = (double)xsr[d + 2] - (double)cr[d + 2];
                double f3 = (double)xsr[d + 3] - (double)cr[d + 3];
                a0 += f0 * f0; a1 += f1 * f1; a2 += f2 * f2; a3 += f3 * f3;
            }
            double dist = (a0 + a1) + (a2 + a3);
            if (dist < bestv || (dist == bestv && k < bestk)) { bestv = dist; bestk = k; }
        }
        sv[t] = bestv; si[t] = bestk;
        __syncthreads();
        for (int s = 128; s > 0; s >>= 1) {
            if (t < s) {
                if (sv[t + s] < sv[t] || (sv[t + s] == sv[t] && si[t + s] < si[t])) {
                    sv[t] = sv[t + s]; si[t] = si[t + s];
                }
            }
            __syncthreads();
        }
        if (t == 0) labels[g] = si[0];
    }
}

// ------- parallel stable counting sort: hist -> scan -> scatter ------------
// Stage 1: per-64-point-chunk label histogram (LDS atomics, 1 wave/block)
__global__ __launch_bounds__(64) void chunk_hist_k(const int* __restrict__ labels,
                                                   int* __restrict__ chunkhist) {
    __shared__ int h[KK];
    const int bc = blockIdx.x;        // b*NCH + c
    const int b  = bc >> 7;
    const int c  = bc & (NCH - 1);
    const int t  = threadIdx.x;
    for (int k = t; k < KK; k += 64) h[k] = 0;
    __syncthreads();
    int l = labels[b * NN + c * 64 + t];
    atomicAdd(&h[l], 1);
    __syncthreads();
    int* ch = chunkhist + (size_t)bc * KK;
    for (int k = t; k < KK; k += 64) ch[k] = h[k];
}

// Stage 2: in-place exclusive prefix over chunks per (b,k) + global offsets
__global__ __launch_bounds__(512) void scan_k(int* __restrict__ chunkhist,
                                              int* __restrict__ counts,
                                              int* __restrict__ offsets) {
    __shared__ int s[KK];
    const int b = blockIdx.x;
    const int k = threadIdx.x;
    int* ch = chunkhist + (size_t)b * NCH * KK;
    int run = 0;
    for (int c = 0; c < NCH; ++c) {
        int v = ch[(size_t)c * KK + k];
        ch[(size_t)c * KK + k] = run;
        run += v;
    }
    counts[b * KK + k] = run;
    s[k] = run;
    __syncthreads();
    // Hillis-Steele inclusive scan over 512 totals
    for (int off = 1; off < KK; off <<= 1) {
        int v = (k >= off) ? s[k - off] : 0;
        __syncthreads();
        s[k] += v;
        __syncthreads();
    }
    offsets[b * KK + k] = s[k] - run;   // exclusive
}

// Stage 3: stable scatter (wave-local rank via shfl, 1 wave/chunk)
__global__ __launch_bounds__(64) void scatter_k(const int* __restrict__ labels,
                                                const int* __restrict__ chunkhist,
                                                const int* __restrict__ offsets,
                                                int* __restrict__ idxlist) {
    const int bc = blockIdx.x;
    const int b  = bc >> 7;
    const int c  = bc & (NCH - 1);
    const int t  = threadIdx.x;
    const int n  = c * 64 + t;
    const int l  = labels[b * NN + n];
    int rank = 0;
    for (int j = 0; j < 64; ++j) {
        int lj = __shfl(l, j, 64);
        rank += (lj == l && j < t) ? 1 : 0;
    }
    int base = offsets[b * KK + l] + chunkhist[(size_t)bc * KK + l];
    idxlist[b * NN + base + rank] = n;
}

// ------- centers update: ordered (n-ascending) sums → deterministic --------
__global__ __launch_bounds__(256) void centers_update_k(const float* __restrict__ x,
                                                        float* __restrict__ centers,
                                                        const int* __restrict__ counts,
                                                        const int* __restrict__ offsets,
                                                        const int* __restrict__ idxlist,
                                                        int* __restrict__ flagcnt) {
    const int bk = blockIdx.x;
    const int b  = bk >> 9;
    const int d  = threadIdx.x;
    if (bk == 0 && d == 0) flagcnt[0] = 0;   // reset for next assign pass
    const int cnt = counts[bk];
    if (cnt > 0) {
        const int* il = idxlist + b * NN + offsets[bk];
        float s = 0.f;
        for (int j = 0; j < cnt; ++j) {
            int n = il[j];
            s = __fadd_rn(s, x[((size_t)b * NN + n) * DD + d]);
        }
        centers[(size_t)bk * DD + d] = s / (float)cnt;
    }
}

__global__ __launch_bounds__(256) void labels_to_float_k(const int* __restrict__ labels,
                                                         float* __restrict__ out) {
    int i = blockIdx.x * 256 + threadIdx.x;
    out[i] = (float)labels[i];
}

__global__ __launch_bounds__(256) void copy_centers_k(const float* __restrict__ centers,
                                                      float* __restrict__ out) {
    size_t i = (size_t)blockIdx.x * 256 + threadIdx.x;
    out[i] = centers[i];
}

extern "C" void kernel_launch(void* const* d_in, const int* in_sizes, int n_in,
                              void* d_out, int out_size, void* d_ws, size_t ws_size,
                              hipStream_t stream) {
    const float* x = (const float*)d_in[0];
    float* out = (float*)d_out;
    float* ws  = (float*)d_ws;

    // ws layout
    float* centers  = ws;                                   // BB*KK*DD
    float* c2       = centers + (size_t)BB * KK * DD;       // BB*KK
    float* x2       = c2 + BB * KK;                         // BB*NN
    int*   labels   = (int*)(x2 + BB * NN);                 // BB*NN
    int*   flagcnt  = labels + BB * NN;                     // 64
    int*   flaglist = flagcnt + 64;                         // BB*NN
    int*   counts   = flaglist + BB * NN;                   // BB*KK
    int*   offsets  = counts + BB * KK;                     // BB*KK
    int*   idxlist  = offsets + BB * KK;                    // BB*NN
    int*   chunkhist= idxlist + BB * NN;                    // BB*NCH*KK

    hipMemsetAsync(flagcnt, 0, 64 * sizeof(int), stream);

    init_centers_k<<<BB * KK, 256, 0, stream>>>(x, centers);
    rowsumsq_k<<<(BB * NN + 255) / 256, 256, 0, stream>>>(x, x2, BB * NN);

    for (int it = 0; it < NITERS; ++it) {
        rowsumsq_k<<<(BB * KK + 255) / 256, 256, 0, stream>>>(centers, c2, BB * KK);
        assign_k<<<BB * (NN / MT), 256, 0, stream>>>(x, centers, x2, c2,
                                                     labels, flagcnt, flaglist);
        refine_k<<<64, 256, 0, stream>>>(x, centers, flagcnt, flaglist, labels);
        chunk_hist_k<<<BB * NCH, 64, 0, stream>>>(labels, chunkhist);
        scan_k<<<BB, 512, 0, stream>>>(chunkhist, counts, offsets);
        scatter_k<<<BB * NCH, 64, 0, stream>>>(labels, chunkhist, offsets, idxlist);
        centers_update_k<<<BB * KK, 256, 0, stream>>>(x, centers, counts, offsets,
                                                      idxlist, flagcnt);
    }

    rowsumsq_k<<<(BB * KK + 255) / 256, 256, 0, stream>>>(centers, c2, BB * KK);
    assign_k<<<BB * (NN / MT), 256, 0, stream>>>(x, centers, x2, c2,
                                                 labels, flagcnt, flaglist);
    refine_k<<<64, 256, 0, stream>>>(x, centers, flagcnt, flaglist, labels);

    labels_to_float_k<<<BB * NN / 256, 256, 0, stream>>>(labels, out);
    copy_centers_k<<<BB * KK * DD / 256, 256, 0, stream>>>(centers, out + BB * NN);
}

// Round 4
// 2255.469 us; speedup vs baseline: 2.5499x; 1.2869x over previous
//
#include <hip/hip_runtime.h>
#include <math.h>

#define BB 4
#define NN 8192
#define DD 256
#define KK 512
#define NITERS 10

#define MT 64     // points per block in assign
#define KT 128    // clusters per k-chunk
#define DC 32     // d chunk staged in LDS

#define XSTR 68   // padded LDS stride for xs[d][m]
#define CSTR 132  // padded LDS stride for cs[d][k]
#define TAU 0.0625f   // top2 margin below which we re-rank in f64

#define NCH 128   // 64-point chunks per batch (NN/64)

// ---------------- init: centers0 = x[:, :K, :] ----------------
__global__ __launch_bounds__(256) void init_centers_k(const float* __restrict__ x,
                                                      float* __restrict__ centers) {
    int bk = blockIdx.x;
    int b  = bk >> 9;
    int k  = bk & 511;
    centers[(size_t)bk * DD + threadIdx.x] = x[((size_t)b * NN + k) * DD + threadIdx.x];
}

// ---------------- row sum of squares, numpy-pairwise order ----------------
__global__ __launch_bounds__(256) void rowsumsq_k(const float* __restrict__ rows,
                                                  float* __restrict__ out, int nrows) {
    int r = blockIdx.x * 256 + threadIdx.x;
    if (r >= nrows) return;
    const float* p = rows + (size_t)r * DD;
    float total = 0.f;
    #pragma unroll
    for (int h = 0; h < 2; ++h) {
        float a[8];
        #pragma unroll
        for (int j = 0; j < 8; ++j) a[j] = 0.f;
        for (int i = 0; i < 128; i += 8) {
            #pragma unroll
            for (int j = 0; j < 8; ++j) {
                float v  = p[h * 128 + i + j];
                float sq = __fmul_rn(v, v);
                a[j] = __fadd_rn(a[j], sq);
            }
        }
        float s = __fadd_rn(__fadd_rn(__fadd_rn(a[0], a[1]), __fadd_rn(a[2], a[3])),
                            __fadd_rn(__fadd_rn(a[4], a[5]), __fadd_rn(a[6], a[7])));
        total = __fadd_rn(total, s);
    }
    out[r] = total;
}

// ---------------- fused distance / top-2 argmin, flag marginal points ------
__global__ __launch_bounds__(256) void assign_k(
    const float* __restrict__ x, const float* __restrict__ centers,
    const float* __restrict__ x2g, const float* __restrict__ c2g,
    int* __restrict__ labels, int* __restrict__ flagcnt, int* __restrict__ flaglist)
{
    __shared__ float xs[DC][XSTR];
    __shared__ float cs[DC][CSTR];

    const int tid = threadIdx.x;
    const int tk  = tid & 15;
    const int tm  = tid >> 4;
    const int bx  = blockIdx.x;
    const int b   = bx >> 7;
    const int m0  = (bx & 127) * MT;

    const float* xb = x       + (size_t)b * NN * DD;
    const float* cb = centers + (size_t)b * KK * DD;

    float x2m[4];
    #pragma unroll
    for (int i = 0; i < 4; ++i) x2m[i] = x2g[b * NN + m0 + tm * 4 + i];

    float rv1[4], rv2[4];
    int   rk1[4];
    #pragma unroll
    for (int i = 0; i < 4; ++i) { rv1[i] = __builtin_inff(); rv2[i] = __builtin_inff(); rk1[i] = 0x7fffffff; }

    const int lrow = tid >> 3;
    const int lcol = (tid & 7) * 4;

    for (int kc = 0; kc < KK; kc += KT) {
        float acc[4][8];
        #pragma unroll
        for (int i = 0; i < 4; ++i)
            #pragma unroll
            for (int j = 0; j < 8; ++j) acc[i][j] = 0.f;

        for (int d0 = 0; d0 < DD; d0 += DC) {
            __syncthreads();
            #pragma unroll
            for (int p = 0; p < 2; ++p) {
                int r = lrow + p * 32;
                float4 v = *(const float4*)(xb + (size_t)(m0 + r) * DD + d0 + lcol);
                xs[lcol + 0][r] = v.x; xs[lcol + 1][r] = v.y;
                xs[lcol + 2][r] = v.z; xs[lcol + 3][r] = v.w;
            }
            #pragma unroll
            for (int p = 0; p < 4; ++p) {
                int r = lrow + p * 32;
                float4 v = *(const float4*)(cb + (size_t)(kc + r) * DD + d0 + lcol);
                cs[lcol + 0][r] = v.x; cs[lcol + 1][r] = v.y;
                cs[lcol + 2][r] = v.z; cs[lcol + 3][r] = v.w;
            }
            __syncthreads();
            #pragma unroll
            for (int d = 0; d < DC; ++d) {
                const float4 xv  = *(const float4*)&xs[d][tm * 4];
                const float4 ca  = *(const float4*)&cs[d][tk * 4];
                const float4 cbv = *(const float4*)&cs[d][64 + tk * 4];
                float xf[4] = {xv.x, xv.y, xv.z, xv.w};
                float cf[8] = {ca.x, ca.y, ca.z, ca.w, cbv.x, cbv.y, cbv.z, cbv.w};
                #pragma unroll
                for (int i = 0; i < 4; ++i)
                    #pragma unroll
                    for (int j = 0; j < 8; ++j)
                        acc[i][j] += xf[i] * cf[j];
            }
        }

        float c2v[8];
        #pragma unroll
        for (int j = 0; j < 4; ++j) c2v[j]     = c2g[b * KK + kc + tk * 4 + j];
        #pragma unroll
        for (int j = 0; j < 4; ++j) c2v[4 + j] = c2g[b * KK + kc + 64 + tk * 4 + j];

        #pragma unroll
        for (int i = 0; i < 4; ++i) {
            float v1 = __builtin_inff(), v2 = __builtin_inff();
            int   k1 = 0x7fffffff;
            #pragma unroll
            for (int j = 0; j < 8; ++j) {
                int kidx = kc + ((j < 4) ? (tk * 4 + j) : (64 + tk * 4 + (j - 4)));
                float t    = __fmul_rn(2.0f, acc[i][j]);
                float cand = __fadd_rn(__fsub_rn(x2m[i], t), c2v[j]);
                if (cand < v1 || (cand == v1 && kidx < k1)) { v2 = v1; v1 = cand; k1 = kidx; }
                else if (cand < v2) v2 = cand;
            }
            #pragma unroll
            for (int off = 1; off < 16; off <<= 1) {
                float ov1 = __shfl_xor(v1, off, 64);
                int   ok1 = __shfl_xor(k1, off, 64);
                float ov2 = __shfl_xor(v2, off, 64);
                if (ov1 < v1 || (ov1 == v1 && ok1 < k1)) { v2 = fminf(v1, ov2); v1 = ov1; k1 = ok1; }
                else { v2 = fminf(v2, ov1); }
            }
            if (v1 < rv1[i] || (v1 == rv1[i] && k1 < rk1[i])) {
                rv2[i] = fminf(rv1[i], v2); rv1[i] = v1; rk1[i] = k1;
            } else {
                rv2[i] = fminf(rv2[i], v1);
            }
        }
    }

    if (tk == 0) {
        #pragma unroll
        for (int i = 0; i < 4; ++i) {
            int g = b * NN + m0 + tm * 4 + i;
            labels[g] = rk1[i];
            if (rv2[i] - rv1[i] < TAU) {
                int pos = atomicAdd(flagcnt, 1);
                flaglist[pos] = g;
            }
        }
    }
}

// ---------------- exact (f64) re-rank of flagged points --------------------
__global__ __launch_bounds__(256) void refine_k(const float* __restrict__ x,
                                                const float* __restrict__ centers,
                                                const int* __restrict__ flagcnt,
                                                const int* __restrict__ flaglist,
                                                int* __restrict__ labels) {
    __shared__ float  xsr[DD];
    __shared__ double sv[256];
    __shared__ int    si[256];
    const int t = threadIdx.x;
    const int cnt = flagcnt[0];
    for (int idx = blockIdx.x; idx < cnt; idx += gridDim.x) {
        const int g = flaglist[idx];
        const int b = g >> 13;
        __syncthreads();
        xsr[t] = x[(size_t)g * DD + t];
        __syncthreads();
        const float* cbase = centers + (size_t)b * KK * DD;
        double bestv = 1e300; int bestk = 0x7fffffff;
        #pragma unroll
        for (int h = 0; h < 2; ++h) {
            int k = t + h * 256;
            const float* cr = cbase + (size_t)k * DD;
            double a0 = 0, a1 = 0, a2 = 0, a3 = 0;
            for (int d = 0; d < DD; d += 4) {
                double f0 = (double)xsr[d + 0] - (double)cr[d + 0];
                double f1 = (double)xsr[d + 1] - (double)cr[d + 1];
                double f2 = (double)xsr[d + 2] - (double)cr[d + 2];
                double f3 = (double)xsr[d + 3] - (double)cr[d + 3];
                a0 += f0 * f0; a1 += f1 * f1; a2 += f2 * f2; a3 += f3 * f3;
            }
            double dist = (a0 + a1) + (a2 + a3);
            if (dist < bestv || (dist == bestv && k < bestk)) { bestv = dist; bestk = k; }
        }
        sv[t] = bestv; si[t] = bestk;
        __syncthreads();
        for (int s = 128; s > 0; s >>= 1) {
            if (t < s) {
                if (sv[t + s] < sv[t] || (sv[t + s] == sv[t] && si[t + s] < si[t])) {
                    sv[t] = sv[t + s]; si[t] = si[t + s];
                }
            }
            __syncthreads();
        }
        if (t == 0) labels[g] = si[0];
    }
}

// ------- parallel stable counting sort: hist -> scan -> scatter ------------
__global__ __launch_bounds__(64) void chunk_hist_k(const int* __restrict__ labels,
                                                   int* __restrict__ chunkhist) {
    __shared__ int h[KK];
    const int bc = blockIdx.x;        // b*NCH + c
    const int b  = bc >> 7;
    const int c  = bc & (NCH - 1);
    const int t  = threadIdx.x;
    for (int k = t; k < KK; k += 64) h[k] = 0;
    __syncthreads();
    int l = labels[b * NN + c * 64 + t];
    atomicAdd(&h[l], 1);
    __syncthreads();
    int* ch = chunkhist + (size_t)bc * KK;
    for (int k = t; k < KK; k += 64) ch[k] = h[k];
}

__global__ __launch_bounds__(512) void scan_k(int* __restrict__ chunkhist,
                                              int* __restrict__ counts,
                                              int* __restrict__ offsets) {
    __shared__ int s[KK];
    const int b = blockIdx.x;
    const int k = threadIdx.x;
    int* ch = chunkhist + (size_t)b * NCH * KK;
    int run = 0;
    for (int c = 0; c < NCH; ++c) {
        int v = ch[(size_t)c * KK + k];
        ch[(size_t)c * KK + k] = run;
        run += v;
    }
    counts[b * KK + k] = run;
    s[k] = run;
    __syncthreads();
    for (int off = 1; off < KK; off <<= 1) {
        int v = (k >= off) ? s[k - off] : 0;
        __syncthreads();
        s[k] += v;
        __syncthreads();
    }
    offsets[b * KK + k] = s[k] - run;   // exclusive
}

__global__ __launch_bounds__(64) void scatter_k(const int* __restrict__ labels,
                                                const int* __restrict__ chunkhist,
                                                const int* __restrict__ offsets,
                                                int* __restrict__ idxlist) {
    const int bc = blockIdx.x;
    const int b  = bc >> 7;
    const int c  = bc & (NCH - 1);
    const int t  = threadIdx.x;
    const int n  = c * 64 + t;
    const int l  = labels[b * NN + n];
    int rank = 0;
    for (int j = 0; j < 64; ++j) {
        int lj = __shfl(l, j, 64);
        rank += (lj == l && j < t) ? 1 : 0;
    }
    int base = offsets[b * KK + l] + chunkhist[(size_t)bc * KK + l];
    idxlist[b * NN + base + rank] = n;
}

// ------- centers update: member-parallel (16 waves), deterministic ---------
// Wave w sums members j = w, w+16, ... ; 64 lanes x float4 cover the 256-dim
// row. Partials combined in fixed ascending-wave order -> deterministic.
__global__ __launch_bounds__(1024) void centers_update_k(const float* __restrict__ x,
                                                         float* __restrict__ centers,
                                                         const int* __restrict__ counts,
                                                         const int* __restrict__ offsets,
                                                         const int* __restrict__ idxlist,
                                                         int* __restrict__ flagcnt) {
    __shared__ float part[16][DD];
    const int bk   = blockIdx.x;
    const int b    = bk >> 9;
    const int tid  = threadIdx.x;
    const int w    = tid >> 6;        // 0..15
    const int lane = tid & 63;
    if (bk == 0 && tid == 0) flagcnt[0] = 0;   // reset for next assign pass
    const int cnt = counts[bk];
    if (cnt == 0) return;             // uniform across block
    const int* il = idxlist + b * NN + offsets[bk];
    const float* xb = x + (size_t)b * NN * DD;
    float4 acc = {0.f, 0.f, 0.f, 0.f};
    for (int j = w; j < cnt; j += 16) {
        int n = il[j];
        float4 v = *(const float4*)(xb + (size_t)n * DD + lane * 4);
        acc.x = __fadd_rn(acc.x, v.x);
        acc.y = __fadd_rn(acc.y, v.y);
        acc.z = __fadd_rn(acc.z, v.z);
        acc.w = __fadd_rn(acc.w, v.w);
    }
    *(float4*)&part[w][lane * 4] = acc;
    __syncthreads();
    if (tid < DD) {
        float s = 0.f;
        #pragma unroll
        for (int w2 = 0; w2 < 16; ++w2) s = __fadd_rn(s, part[w2][tid]);
        centers[(size_t)bk * DD + tid] = s / (float)cnt;
    }
}

__global__ __launch_bounds__(256) void labels_to_float_k(const int* __restrict__ labels,
                                                         float* __restrict__ out) {
    int i = blockIdx.x * 256 + threadIdx.x;
    out[i] = (float)labels[i];
}

__global__ __launch_bounds__(256) void copy_centers_k(const float* __restrict__ centers,
                                                      float* __restrict__ out) {
    size_t i = (size_t)blockIdx.x * 256 + threadIdx.x;
    out[i] = centers[i];
}

extern "C" void kernel_launch(void* const* d_in, const int* in_sizes, int n_in,
                              void* d_out, int out_size, void* d_ws, size_t ws_size,
                              hipStream_t stream) {
    const float* x = (const float*)d_in[0];
    float* out = (float*)d_out;
    float* ws  = (float*)d_ws;

    // ws layout
    float* centers  = ws;                                   // BB*KK*DD
    float* c2       = centers + (size_t)BB * KK * DD;       // BB*KK
    float* x2       = c2 + BB * KK;                         // BB*NN
    int*   labels   = (int*)(x2 + BB * NN);                 // BB*NN
    int*   flagcnt  = labels + BB * NN;                     // 64
    int*   flaglist = flagcnt + 64;                         // BB*NN
    int*   counts   = flaglist + BB * NN;                   // BB*KK
    int*   offsets  = counts + BB * KK;                     // BB*KK
    int*   idxlist  = offsets + BB * KK;                    // BB*NN
    int*   chunkhist= idxlist + BB * NN;                    // BB*NCH*KK

    hipMemsetAsync(flagcnt, 0, 64 * sizeof(int), stream);

    init_centers_k<<<BB * KK, 256, 0, stream>>>(x, centers);
    rowsumsq_k<<<(BB * NN + 255) / 256, 256, 0, stream>>>(x, x2, BB * NN);

    for (int it = 0; it < NITERS; ++it) {
        rowsumsq_k<<<(BB * KK + 255) / 256, 256, 0, stream>>>(centers, c2, BB * KK);
        assign_k<<<BB * (NN / MT), 256, 0, stream>>>(x, centers, x2, c2,
                                                     labels, flagcnt, flaglist);
        refine_k<<<64, 256, 0, stream>>>(x, centers, flagcnt, flaglist, labels);
        chunk_hist_k<<<BB * NCH, 64, 0, stream>>>(labels, chunkhist);
        scan_k<<<BB, 512, 0, stream>>>(chunkhist, counts, offsets);
        scatter_k<<<BB * NCH, 64, 0, stream>>>(labels, chunkhist, offsets, idxlist);
        centers_update_k<<<BB * KK, 1024, 0, stream>>>(x, centers, counts, offsets,
                                                       idxlist, flagcnt);
    }

    rowsumsq_k<<<(BB * KK + 255) / 256, 256, 0, stream>>>(centers, c2, BB * KK);
    assign_k<<<BB * (NN / MT), 256, 0, stream>>>(x, centers, x2, c2,
                                                 labels, flagcnt, flaglist);
    refine_k<<<64, 256, 0, stream>>>(x, centers, flagcnt, flaglist, labels);

    labels_to_float_k<<<BB * NN / 256, 256, 0, stream>>>(labels, out);
    copy_centers_k<<<BB * KK * DD / 256, 256, 0, stream>>>(centers, out + BB * NN);
}